// Round 9
// baseline (2423.616 us; speedup 1.0000x reference)
//
#include <hip/hip_runtime.h>
#include <hip/hip_bf16.h>

// GatedMatchRNN: B=32, L1=128, L2=512, H=256
// Round 9: 2 barriers/step. Blocks exchange ONLY ctp (attention partials) and
// gpw (gate partials: Wih-col-slice@li + Whh-col-slice@h). Every block then
// computes the full gates/h/c/q locally (bit-identical across blocks -> no
// h/q/li communication, no 3rd barrier). XCD-local mapping (b=blk&31),
// RMW-arrive + load-poll barrier (r8-proven), bf16 weights incl. Wvp.

#define B_ 32
#define L1_ 128
#define L2_ 512
#define H_ 256
#define GRP 8
#define TB 512
#define LOG2E_ 1.4426950408889634f

// ws layout (bytes)
#define YP_OFF   0u                         // bf16 [32][512][256] = 8 MB
#define XUP_OFF  (8u << 20)                 // bf16 [32][128][256] = 2 MB
#define CTP_OFF  (10u << 20)                // f32 [32][8][256] = 256 KB
#define ES_OFF   (CTP_OFF + (256u << 10))   // f32 [32][8] (padded 4 KB)
#define GPW_OFF  (ES_OFF + (4u << 10))      // f32 [32][8][1024] = 1 MB
#define BAR_OFF  (GPW_OFF + (1024u << 10))  // uint counters [32][32] = 4 KB
#define WGB_OFF  (BAR_OFF + (4u << 10))     // bf16 Wg = 512 KB
#define WIHB_OFF (WGB_OFF + (512u << 10))   // bf16 Wih = 1 MB
#define WHHB_OFF (WIHB_OFF + (1024u << 10)) // bf16 Whh = 512 KB
#define WVPB_OFF (WHHB_OFF + (512u << 10))  // bf16 Wvp = 128 KB
// end ~13.4 MB (ws >= 16 MB, proven round 2)

__device__ __forceinline__ float fexp2(float x) {
#if __has_builtin(__builtin_amdgcn_exp2f)
  return __builtin_amdgcn_exp2f(x);
#else
  return exp2f(x);
#endif
}
__device__ __forceinline__ float frcp(float x) {
#if __has_builtin(__builtin_amdgcn_rcpf)
  return __builtin_amdgcn_rcpf(x);
#else
  return 1.0f / x;
#endif
}
__device__ __forceinline__ float ftanh(float x) {
  return 1.0f - 2.0f * frcp(1.0f + fexp2(x * (2.0f * LOG2E_)));
}
__device__ __forceinline__ float fsig(float x) {
  return frcp(1.0f + fexp2(-x * LOG2E_));
}
__device__ __forceinline__ float dot4(float4 a, float4 b) {
  return a.x * b.x + a.y * b.y + a.z * b.z + a.w * b.w;
}
__device__ __forceinline__ float bfl(unsigned u) {
  return __uint_as_float(u << 16);
}
__device__ __forceinline__ float bfh(unsigned u) {
  return __uint_as_float(u & 0xffff0000u);
}
__device__ __forceinline__ unsigned short f2bf(float f) {
  __hip_bfloat16 b = __float2bfloat16(f);
  return *reinterpret_cast<unsigned short*>(&b);
}

// Per-access device-coherent load/store (sc0 sc1). No cache invalidates.
__device__ __forceinline__ float cload(const float* p) {
  return __hip_atomic_load(p, __ATOMIC_RELAXED, __HIP_MEMORY_SCOPE_AGENT);
}
__device__ __forceinline__ void cstore(float* p, float v) {
  __hip_atomic_store(p, v, __ATOMIC_RELAXED, __HIP_MEMORY_SCOPE_AGENT);
}

// r8-proven barrier: all-wave vmcnt drain -> RMW arrive -> relaxed load poll.
__device__ __forceinline__ void group_barrier(unsigned* cnt, unsigned target) {
  asm volatile("s_waitcnt vmcnt(0)" ::: "memory");
  __syncthreads();
  if (threadIdx.x == 0) {
    __hip_atomic_fetch_add(cnt, 1u, __ATOMIC_RELAXED,
                           __HIP_MEMORY_SCOPE_AGENT);
    while (__hip_atomic_load(cnt, __ATOMIC_RELAXED,
                             __HIP_MEMORY_SCOPE_AGENT) < GRP * target) {
      __builtin_amdgcn_s_sleep(1);
    }
  }
  __syncthreads();
  asm volatile("" ::: "memory");
}

// ---------------------------------------------------------------------------
// Projection: blocks 0..511 -> yp (bf16), 512..639 -> xup (bf16).
// ---------------------------------------------------------------------------
__global__ __launch_bounds__(256) void proj_kernel(
    const float* __restrict__ y, const float* __restrict__ Wq,
    const float* __restrict__ bq, const float* __restrict__ x,
    const float* __restrict__ Wup, const float* __restrict__ bup,
    __hip_bfloat16* __restrict__ yp, __hip_bfloat16* __restrict__ xup) {
  __shared__ float As[32 * 256];
  const int blk = blockIdx.x;
  const int tid = threadIdx.x;
  const float* src;
  const float* W;
  const float* bias;
  __hip_bfloat16* dst;
  int row0;
  if (blk < 512) {
    src = y; W = Wq; bias = bq; dst = yp; row0 = blk * 32;
  } else {
    src = x; W = Wup; bias = bup; dst = xup; row0 = (blk - 512) * 32;
  }
  const float4* s4 = (const float4*)(src + (size_t)row0 * H_);
  float4* A4 = (float4*)As;
#pragma unroll
  for (int i = 0; i < 8; ++i) A4[i * 256 + tid] = s4[i * 256 + tid];
  __syncthreads();

  const float4* w4 = (const float4*)(W + (size_t)tid * H_);
  float acc[32];
#pragma unroll
  for (int r = 0; r < 32; ++r) acc[r] = 0.0f;
  for (int kc = 0; kc < 64; ++kc) {
    float4 w = w4[kc];
#pragma unroll
    for (int r = 0; r < 32; ++r) acc[r] += dot4(A4[r * 64 + kc], w);
  }
  const float bb = bias[tid];
#pragma unroll 4
  for (int r = 0; r < 32; ++r)
    dst[(size_t)(row0 + r) * H_ + tid] = __float2bfloat16(acc[r] + bb);
}

// ---------------------------------------------------------------------------
// Weight conversion: Wg, Wih, Whh, Wvp -> bf16 in ws. 1088 blocks x 256 thr.
// ---------------------------------------------------------------------------
__global__ __launch_bounds__(256) void wconv_kernel(
    const float* __restrict__ Wg, const float* __restrict__ Wih,
    const float* __restrict__ Whh, const float* __restrict__ Wvp,
    unsigned short* __restrict__ wgb, unsigned short* __restrict__ wihb,
    unsigned short* __restrict__ whhb, unsigned short* __restrict__ wvpb) {
  const int e = blockIdx.x * 256 + threadIdx.x;  // float4 index
  const float* src;
  unsigned short* dst;
  int off;
  if (e < 65536) {
    src = Wg; dst = wgb; off = e;
  } else if (e < 196608) {
    src = Wih; dst = wihb; off = e - 65536;
  } else if (e < 262144) {
    src = Whh; dst = whhb; off = e - 196608;
  } else {
    src = Wvp; dst = wvpb; off = e - 262144;
  }
  float4 v = ((const float4*)src)[off];
  ushort4 o;
  o.x = f2bf(v.x); o.y = f2bf(v.y); o.z = f2bf(v.z); o.w = f2bf(v.w);
  ((ushort4*)dst)[off] = o;
}

// ---------------------------------------------------------------------------
// Scan: block (b,g); b = blk&31 (XCD-local groups), g = blk>>5. 512 threads.
// ---------------------------------------------------------------------------
__global__ __launch_bounds__(TB) void scan_kernel(
    const float* __restrict__ x, const int* __restrict__ x_mask,
    const float* __restrict__ y, const int* __restrict__ y_mask,
    const float* __restrict__ h0, const float* __restrict__ c0,
    const float* __restrict__ bvp, const float* __restrict__ Vw,
    const float* __restrict__ Vb, const float* __restrict__ bg,
    const float* __restrict__ bih, const float* __restrict__ bhh,
    char* __restrict__ ws, float* __restrict__ out) {
  const int blk = blockIdx.x;
  const int b = blk & 31;   // batch; its 8 g-blocks share one XCD
  const int g = blk >> 5;   // slice
  const int tid = threadIdx.x;

  const __hip_bfloat16* yp = (const __hip_bfloat16*)(ws + YP_OFF);
  const unsigned short* xupb = (const unsigned short*)(ws + XUP_OFF);
  float* ctp = (float*)(ws + CTP_OFF);
  float* esb = (float*)(ws + ES_OFF);
  float* gpw = (float*)(ws + GPW_OFF);
  unsigned* cnt = (unsigned*)(ws + BAR_OFF) + b * 32;  // 128B per batch
  const unsigned short* wgb = (const unsigned short*)(ws + WGB_OFF);
  const unsigned short* wihb = (const unsigned short*)(ws + WIHB_OFF);
  const unsigned short* whhb = (const unsigned short*)(ws + WHHB_OFF);
  const unsigned short* wvpb = (const unsigned short*)(ws + WVPB_OFF);

  __shared__ uint4 yp_lds[64 * 32];  // 32 KB, XOR-swizzled bf16 rows
  __shared__ float y_lds[64 * 256];  // 64 KB
  __shared__ __align__(16) float h_s[H_];   // full h (local, all blocks)
  __shared__ __align__(16) float c_s[H_];   // full c (local)
  __shared__ float q_s[H_];
  __shared__ float v_s[H_];
  __shared__ float bvp_s[H_];
  __shared__ __align__(16) float mg_s[2 * H_];
  __shared__ __align__(16) float li_s[64];  // own li slice (local only)
  __shared__ float gate_s[1024];
  __shared__ float bi_s[1024];
  __shared__ float red_s[64 * 9];
  __shared__ float e_s[64];
  __shared__ float esum_s[8];
  __shared__ float bg_s[64];
  __shared__ int ym_s[64];
  __shared__ int xm_s[L1_];

  // ---- stage t-invariant data ----
  {
    const uint4* src = (const uint4*)(yp + (size_t)(b * L2_ + g * 64) * H_);
    for (int k = tid; k < 64 * 32; k += TB) {
      int r = k >> 5, c = k & 31;
      yp_lds[r * 32 + (c ^ (r & 31))] = src[k];  // swizzle kills bank conflicts
    }
    const float4* ys = (const float4*)(y + (size_t)(b * L2_ + g * 64) * H_);
    float4* yd = (float4*)y_lds;
    for (int k = tid; k < 64 * 64; k += TB) yd[k] = ys[k];
  }
  if (tid < H_) {
    v_s[tid] = Vw[tid];
    bvp_s[tid] = bvp[tid];
    h_s[tid] = h0[b * H_ + tid];
    c_s[tid] = c0[b * H_ + tid];
  }
  if (tid < 64) {
    ym_s[tid] = y_mask[b * L2_ + g * 64 + tid];
    bg_s[tid] = bg[g * 64 + tid];
  }
  if (tid < 128) xm_s[tid] = x_mask[b * L1_ + tid];
  bi_s[tid] = bih[tid] + bhh[tid];
  bi_s[tid + 512] = bih[tid + 512] + bhh[tid + 512];
  const float vb = Vb[0];
  __syncthreads();

  unsigned target = 0;

  for (int t = 0; t < L1_; ++t) {
    const int xm = xm_s[t];

    // ---- q = Wvp_bf16 @ h + bvp + xup_t (fully local) ---------------------
    {
      const int j = tid >> 1, sub = tid & 1;
      const uint4* wv = (const uint4*)(wvpb + (size_t)j * H_) + sub * 16;
      const float4* h4 = (const float4*)h_s + sub * 32;
      float acc = 0.f;
#pragma unroll
      for (int k = 0; k < 16; ++k) {
        uint4 u = wv[k];
        float4 a = h4[2 * k], c2 = h4[2 * k + 1];
        acc += bfl(u.x) * a.x + bfh(u.x) * a.y + bfl(u.y) * a.z +
               bfh(u.y) * a.w + bfl(u.z) * c2.x + bfh(u.z) * c2.y +
               bfl(u.w) * c2.z + bfh(u.w) * c2.w;
      }
      acc += __shfl_xor(acc, 1);
      if (sub == 0)
        q_s[j] = acc + bvp_s[j] + bfl(xupb[(size_t)(b * L1_ + t) * H_ + j]);
    }
    __syncthreads();

    // ---- B: scores for own l-slice [g*64, g*64+64) ------------------------
    {
      const int l = tid & 63, sub = tid >> 6;
      float acc = 0.f;
#pragma unroll
      for (int i = 0; i < 4; ++i) {
        uint4 u = yp_lds[l * 32 + ((sub * 4 + i) ^ (l & 31))];
        const int h = sub * 32 + i * 8;
        acc += v_s[h + 0] * ftanh(q_s[h + 0] + bfl(u.x));
        acc += v_s[h + 1] * ftanh(q_s[h + 1] + bfh(u.x));
        acc += v_s[h + 2] * ftanh(q_s[h + 2] + bfl(u.y));
        acc += v_s[h + 3] * ftanh(q_s[h + 3] + bfh(u.y));
        acc += v_s[h + 4] * ftanh(q_s[h + 4] + bfl(u.z));
        acc += v_s[h + 5] * ftanh(q_s[h + 5] + bfh(u.z));
        acc += v_s[h + 6] * ftanh(q_s[h + 6] + bfl(u.w));
        acc += v_s[h + 7] * ftanh(q_s[h + 7] + bfh(u.w));
      }
      red_s[l * 9 + sub] = acc;  // stride 9 (2-way max, free)
    }
    __syncthreads();
    if (tid < 64) {
      float s = vb;
#pragma unroll
      for (int k = 0; k < 8; ++k) s += red_s[tid * 9 + k];
      // |s| <= |Vb| + sum|v| ~ 13 -> exp never overflows; no global max
      float e = ym_s[tid] ? 0.f : fexp2(s * LOG2E_);
      e_s[tid] = e;
      float ss = e;
#pragma unroll
      for (int off = 32; off >= 1; off >>= 1) ss += __shfl_xor(ss, off);
      if (tid == 0) cstore(&esb[b * 8 + g], ss);
    }
    __syncthreads();

    // ---- ct partial over own l-slice (y from LDS) -------------------------
    {
      const int d = tid & 255, part = tid >> 8;
      float acc = 0.f;
#pragma unroll 8
      for (int i = 0; i < 32; ++i)
        acc += e_s[part * 32 + i] * y_lds[(part * 32 + i) * 256 + d];
      red_s[tid] = acc;
    }
    __syncthreads();
    if (tid < H_)
      cstore(&ctp[(b * 8 + g) * H_ + tid], red_s[tid] + red_s[tid + 256]);
    group_barrier(cnt, ++target);  // --- bar1 ---

    // ---- ct finalize (spread) + merge -------------------------------------
    if (tid < 8) esum_s[tid] = cload(&esb[b * 8 + tid]);
    {
      const int j = tid & 255, half = tid >> 8;
      float acc = 0.f;
#pragma unroll
      for (int k = 0; k < 4; ++k)
        acc += cload(&ctp[(b * 8 + half * 4 + k) * H_ + j]);
      red_s[half * 256 + j] = acc;
      if (tid < H_) mg_s[tid] = x[(size_t)(b * L1_ + t) * H_ + tid];
    }
    __syncthreads();
    if (tid < H_) {
      float tot = esum_s[0] + esum_s[1] + esum_s[2] + esum_s[3] + esum_s[4] +
                  esum_s[5] + esum_s[6] + esum_s[7];
      mg_s[H_ + tid] = (red_s[tid] + red_s[256 + tid]) * frcp(tot);
    }
    __syncthreads();

    // ---- E: own li slice [g*64, g*64+64) (LOCAL, no comm) -----------------
    {
      const int o = tid >> 3, sub = tid & 7;
      const uint4* wrow = (const uint4*)(wgb + (size_t)(g * 64 + o) * 512);
      const float4* m4 = (const float4*)mg_s;
      float acc = 0.f;
#pragma unroll
      for (int j = 0; j < 8; ++j) {
        uint4 u = wrow[sub + 8 * j];
        float4 ma = m4[(sub + 8 * j) * 2], mb = m4[(sub + 8 * j) * 2 + 1];
        acc += bfl(u.x) * ma.x + bfh(u.x) * ma.y + bfl(u.y) * ma.z +
               bfh(u.y) * ma.w + bfl(u.z) * mb.x + bfh(u.z) * mb.y +
               bfl(u.w) * mb.z + bfh(u.w) * mb.w;
      }
      acc += __shfl_xor(acc, 1);
      acc += __shfl_xor(acc, 2);
      acc += __shfl_xor(acc, 4);
      if (sub == 0) {
        float gt = fsig(acc + bg_s[o]);
        li_s[o] = xm ? 0.f : gt * mg_s[g * 64 + o];
      }
    }
    __syncthreads();

    // ---- gp: gate partials for ALL 1024 rows from own li/h col-slices -----
    {
      const float4* l4 = (const float4*)li_s;
      const float4* hb4 = (const float4*)(h_s + g * 32);
#pragma unroll
      for (int rr = 0; rr < 2; ++rr) {
        const int r = tid + rr * 512;
        const uint4* wi = (const uint4*)wihb + (size_t)r * 64 + g * 8;
        const uint4* wh = (const uint4*)whhb + (size_t)r * 32 + g * 4;
        float acc = 0.f;
#pragma unroll
        for (int j = 0; j < 8; ++j) {
          uint4 u = wi[j];
          float4 a = l4[2 * j], c2 = l4[2 * j + 1];
          acc += bfl(u.x) * a.x + bfh(u.x) * a.y + bfl(u.y) * a.z +
                 bfh(u.y) * a.w + bfl(u.z) * c2.x + bfh(u.z) * c2.y +
                 bfl(u.w) * c2.z + bfh(u.w) * c2.w;
        }
#pragma unroll
        for (int j = 0; j < 4; ++j) {
          uint4 u = wh[j];
          float4 a = hb4[2 * j], c2 = hb4[2 * j + 1];
          acc += bfl(u.x) * a.x + bfh(u.x) * a.y + bfl(u.y) * a.z +
                 bfh(u.y) * a.w + bfl(u.z) * c2.x + bfh(u.z) * c2.y +
                 bfl(u.w) * c2.z + bfh(u.w) * c2.w;
        }
        cstore(&gpw[(size_t)(b * 8 + g) * 1024 + r], acc);
      }
    }
    group_barrier(cnt, ++target);  // --- bar2 ---

    // ---- gates sum + full pointwise (every block, bit-identical) ----------
#pragma unroll
    for (int rr = 0; rr < 2; ++rr) {
      const int r = tid + rr * 512;
      float s = bi_s[r];
#pragma unroll
      for (int g2 = 0; g2 < 8; ++g2)
        s += cload(&gpw[(size_t)(b * 8 + g2) * 1024 + r]);
      gate_s[r] = s;
    }
    __syncthreads();
    if (tid < H_) {
      float ii = gate_s[tid], ff = gate_s[H_ + tid];
      float gg = gate_s[2 * H_ + tid], oo = gate_s[3 * H_ + tid];
      float cn = fsig(ff) * c_s[tid] + fsig(ii) * ftanh(gg);
      float hn = xm ? 0.f : fsig(oo) * ftanh(cn);
      c_s[tid] = cn;
      h_s[tid] = hn;
      if ((tid >> 5) == g)  // own h-slice -> no duplicate global writes
        out[(size_t)(b * L1_ + t) * H_ + tid] = hn;
    }
    __syncthreads();
  }
}

extern "C" void kernel_launch(void* const* d_in, const int* in_sizes, int n_in,
                              void* d_out, int out_size, void* d_ws,
                              size_t ws_size, hipStream_t stream) {
  const float* x = (const float*)d_in[0];
  const int* x_mask = (const int*)d_in[1];
  const float* y = (const float*)d_in[2];
  const int* y_mask = (const int*)d_in[3];
  const float* h0 = (const float*)d_in[4];
  const float* c0 = (const float*)d_in[5];
  const float* Wq = (const float*)d_in[6];
  const float* bq = (const float*)d_in[7];
  const float* Wup = (const float*)d_in[8];
  const float* bup = (const float*)d_in[9];
  const float* Wvp = (const float*)d_in[10];
  const float* bvp = (const float*)d_in[11];
  const float* Vw = (const float*)d_in[12];
  const float* Vb = (const float*)d_in[13];
  const float* Wg = (const float*)d_in[14];
  const float* bg = (const float*)d_in[15];
  const float* Wih = (const float*)d_in[16];
  const float* Whh = (const float*)d_in[17];
  const float* bih = (const float*)d_in[18];
  const float* bhh = (const float*)d_in[19];

  float* out = (float*)d_out;
  char* ws = (char*)d_ws;

  hipMemsetAsync(ws + BAR_OFF, 0, 4096, stream);  // barrier counters -> 0
  proj_kernel<<<dim3(640), dim3(256), 0, stream>>>(
      y, Wq, bq, x, Wup, bup, (__hip_bfloat16*)(ws + YP_OFF),
      (__hip_bfloat16*)(ws + XUP_OFF));
  wconv_kernel<<<dim3(1088), dim3(256), 0, stream>>>(
      Wg, Wih, Whh, Wvp, (unsigned short*)(ws + WGB_OFF),
      (unsigned short*)(ws + WIHB_OFF), (unsigned short*)(ws + WHHB_OFF),
      (unsigned short*)(ws + WVPB_OFF));
  scan_kernel<<<dim3(B_ * GRP), dim3(TB), 0, stream>>>(
      x, x_mask, y, y_mask, h0, c0, bvp, Vw, Vb, bg, bih, bhh, ws, out);
}

// Round 10
// 1315.057 us; speedup vs baseline: 1.8430x; 1.8430x over previous
//
#include <hip/hip_runtime.h>
#include <hip/hip_bf16.h>

// GatedMatchRNN: B=32, L1=128, L2=512, H=256
// Round 10: r8 structure (GRP=8, 3 barriers, bf16 weights, XCD-local groups
// b=blk&31) with data comm moved from memory-side (sc0sc1) to XCD-local L2:
// plain stores (write-back L2) + sc0-only loads (bypass L1, hit shared L2).
// Barrier counters stay memory-side (proven; never L2-cached -> no cross-
// launch staleness). Math bit-identical to r8.

#define B_ 32
#define L1_ 128
#define L2_ 512
#define H_ 256
#define GRP 8
#define TB 512
#define LOG2E_ 1.4426950408889634f

// ws layout (bytes)
#define YP_OFF   0u                        // bf16 [32][512][256] = 8 MB
#define XUP_OFF  (8u << 20)                // bf16 [32][128][256] = 2 MB
#define QP_OFF   (10u << 20)               // f32 [32][8][256] = 256 KB
#define CTP_OFF  (QP_OFF + (256u << 10))   // f32 [32][8][256] = 256 KB
#define ES_OFF   (CTP_OFF + (256u << 10))  // f32 [32][8] (padded 4 KB)
#define LI_OFF   (ES_OFF + (4u << 10))     // f32 [32][512] = 64 KB
#define HB_OFF   (LI_OFF + (64u << 10))    // f32 [32][256] = 32 KB
#define BAR_OFF  (HB_OFF + (32u << 10))    // uint counters [32][32] = 4 KB
#define WGB_OFF  (BAR_OFF + (4u << 10))    // bf16 Wg = 512 KB
#define WIHB_OFF (WGB_OFF + (512u << 10))  // bf16 Wih = 1 MB
#define WHHB_OFF (WIHB_OFF + (1024u << 10))// bf16 Whh = 512 KB
// end ~12.6 MB (ws >= 16 MB, proven round 2)

__device__ __forceinline__ float fexp2(float x) {
#if __has_builtin(__builtin_amdgcn_exp2f)
  return __builtin_amdgcn_exp2f(x);
#else
  return exp2f(x);
#endif
}
__device__ __forceinline__ float frcp(float x) {
#if __has_builtin(__builtin_amdgcn_rcpf)
  return __builtin_amdgcn_rcpf(x);
#else
  return 1.0f / x;
#endif
}
__device__ __forceinline__ float ftanh(float x) {
  return 1.0f - 2.0f * frcp(1.0f + fexp2(x * (2.0f * LOG2E_)));
}
__device__ __forceinline__ float fsig(float x) {
  return frcp(1.0f + fexp2(-x * LOG2E_));
}
__device__ __forceinline__ float dot4(float4 a, float4 b) {
  return a.x * b.x + a.y * b.y + a.z * b.z + a.w * b.w;
}
__device__ __forceinline__ float bfl(unsigned u) {
  return __uint_as_float(u << 16);
}
__device__ __forceinline__ float bfh(unsigned u) {
  return __uint_as_float(u & 0xffff0000u);
}
__device__ __forceinline__ unsigned short f2bf(float f) {
  __hip_bfloat16 b = __float2bfloat16(f);
  return *reinterpret_cast<unsigned short*>(&b);
}

// ---- XCD-local L2 comm primitives ----
// Plain store: L1 is write-through -> value lands in this XCD's write-back L2.
__device__ __forceinline__ void l2store(float* p, float v) {
  asm volatile("global_store_dword %0, %1, off" ::"v"(p), "v"(v) : "memory");
}
// sc0-only load: bypass L1, read the (shared, same-XCD) L2 copy.
__device__ __forceinline__ float l2load(const float* p) {
  float v;
  asm volatile("global_load_dword %0, %1, off sc0\n\ts_waitcnt vmcnt(0)"
               : "=&v"(v)
               : "v"(p)
               : "memory");
  return v;
}
// 4 batched sc0 loads at byte offsets {0,1024,2048,3072} (= one H_ f32 row
// stride between partial slots), single waitcnt.
__device__ __forceinline__ void l2load4(const float* p, float& a, float& b,
                                        float& c, float& d) {
  asm volatile(
      "global_load_dword %0, %4, off sc0\n\t"
      "global_load_dword %1, %4, off offset:1024 sc0\n\t"
      "global_load_dword %2, %4, off offset:2048 sc0\n\t"
      "global_load_dword %3, %4, off offset:3072 sc0\n\t"
      "s_waitcnt vmcnt(0)"
      : "=&v"(a), "=&v"(b), "=&v"(c), "=&v"(d)
      : "v"(p)
      : "memory");
}

// r8-proven barrier (memory-side counters): all-wave vmcnt drain (now cheap
// L2 acks) -> RMW arrive -> relaxed load poll.
__device__ __forceinline__ void group_barrier(unsigned* cnt, unsigned target) {
  asm volatile("s_waitcnt vmcnt(0)" ::: "memory");
  __syncthreads();
  if (threadIdx.x == 0) {
    __hip_atomic_fetch_add(cnt, 1u, __ATOMIC_RELAXED,
                           __HIP_MEMORY_SCOPE_AGENT);
    while (__hip_atomic_load(cnt, __ATOMIC_RELAXED,
                             __HIP_MEMORY_SCOPE_AGENT) < GRP * target) {
      __builtin_amdgcn_s_sleep(1);
    }
  }
  __syncthreads();
  asm volatile("" ::: "memory");
}

// ---------------------------------------------------------------------------
// Projection: blocks 0..511 -> yp (bf16), 512..639 -> xup (bf16).
// ---------------------------------------------------------------------------
__global__ __launch_bounds__(256) void proj_kernel(
    const float* __restrict__ y, const float* __restrict__ Wq,
    const float* __restrict__ bq, const float* __restrict__ x,
    const float* __restrict__ Wup, const float* __restrict__ bup,
    __hip_bfloat16* __restrict__ yp, __hip_bfloat16* __restrict__ xup) {
  __shared__ float As[32 * 256];
  const int blk = blockIdx.x;
  const int tid = threadIdx.x;
  const float* src;
  const float* W;
  const float* bias;
  __hip_bfloat16* dst;
  int row0;
  if (blk < 512) {
    src = y; W = Wq; bias = bq; dst = yp; row0 = blk * 32;
  } else {
    src = x; W = Wup; bias = bup; dst = xup; row0 = (blk - 512) * 32;
  }
  const float4* s4 = (const float4*)(src + (size_t)row0 * H_);
  float4* A4 = (float4*)As;
#pragma unroll
  for (int i = 0; i < 8; ++i) A4[i * 256 + tid] = s4[i * 256 + tid];
  __syncthreads();

  const float4* w4 = (const float4*)(W + (size_t)tid * H_);
  float acc[32];
#pragma unroll
  for (int r = 0; r < 32; ++r) acc[r] = 0.0f;
  for (int kc = 0; kc < 64; ++kc) {
    float4 w = w4[kc];
#pragma unroll
    for (int r = 0; r < 32; ++r) acc[r] += dot4(A4[r * 64 + kc], w);
  }
  const float bb = bias[tid];
#pragma unroll 4
  for (int r = 0; r < 32; ++r)
    dst[(size_t)(row0 + r) * H_ + tid] = __float2bfloat16(acc[r] + bb);
}

// ---------------------------------------------------------------------------
// Weight conversion: Wg(512x512), Wih(1024x512), Whh(1024x256) -> bf16 in ws.
// ---------------------------------------------------------------------------
__global__ __launch_bounds__(256) void wconv_kernel(
    const float* __restrict__ Wg, const float* __restrict__ Wih,
    const float* __restrict__ Whh, unsigned short* __restrict__ wgb,
    unsigned short* __restrict__ wihb, unsigned short* __restrict__ whhb) {
  const int e = blockIdx.x * 256 + threadIdx.x;  // float4 index
  const float* src;
  unsigned short* dst;
  int off;
  if (e < 65536) {
    src = Wg; dst = wgb; off = e;
  } else if (e < 196608) {
    src = Wih; dst = wihb; off = e - 65536;
  } else {
    src = Whh; dst = whhb; off = e - 196608;
  }
  float4 v = ((const float4*)src)[off];
  ushort4 o;
  o.x = f2bf(v.x); o.y = f2bf(v.y); o.z = f2bf(v.z); o.w = f2bf(v.w);
  ((ushort4*)dst)[off] = o;
}

// ---------------------------------------------------------------------------
// Scan: block (b,g); b = blk&31 (XCD-local groups), g = blk>>5. 512 threads.
// ---------------------------------------------------------------------------
__global__ __launch_bounds__(TB) void scan_kernel(
    const float* __restrict__ x, const int* __restrict__ x_mask,
    const float* __restrict__ y, const int* __restrict__ y_mask,
    const float* __restrict__ h0, const float* __restrict__ c0,
    const float* __restrict__ Wvp, const float* __restrict__ bvp,
    const float* __restrict__ Vw, const float* __restrict__ Vb,
    const float* __restrict__ bg, const float* __restrict__ bih,
    const float* __restrict__ bhh, char* __restrict__ ws,
    float* __restrict__ out) {
  const int blk = blockIdx.x;
  const int b = blk & 31;   // batch; its 8 g-blocks share one XCD (r8-proven)
  const int g = blk >> 5;   // slice
  const int tid = threadIdx.x;

  const __hip_bfloat16* yp = (const __hip_bfloat16*)(ws + YP_OFF);
  const unsigned short* xupb = (const unsigned short*)(ws + XUP_OFF);
  float* qp = (float*)(ws + QP_OFF);
  float* ctp = (float*)(ws + CTP_OFF);
  float* esb = (float*)(ws + ES_OFF);
  float* lib = (float*)(ws + LI_OFF);
  float* hb = (float*)(ws + HB_OFF);
  unsigned* cnt = (unsigned*)(ws + BAR_OFF) + b * 32;  // 128B per batch
  const unsigned short* wgb = (const unsigned short*)(ws + WGB_OFF);
  const unsigned short* wihb = (const unsigned short*)(ws + WIHB_OFF);
  const unsigned short* whhb = (const unsigned short*)(ws + WHHB_OFF);

  __shared__ uint4 yp_lds[64 * 32];  // 32 KB, XOR-swizzled bf16 rows
  __shared__ float y_lds[64 * 256];  // 64 KB
  __shared__ __align__(16) float h_s[H_];
  __shared__ float q_s[H_];
  __shared__ float v_s[H_];
  __shared__ float bvp_s[H_];
  __shared__ float e_s[64];
  __shared__ __align__(16) float mg_s[2 * H_];
  __shared__ __align__(16) float li_s[2 * H_];
  __shared__ float gate_s[128];
  __shared__ float red_s[64 * 9];
  __shared__ float esum_s[8];
  __shared__ __align__(16) float c_s[32];
  __shared__ __align__(16) float hn_s[32];
  __shared__ float bg_s[64];
  __shared__ float bi_s[128];
  __shared__ int ym_s[64];
  __shared__ int xm_s[L1_];

  unsigned target = 0;

  // ---- stage t-invariant data ----
  {
    const uint4* src = (const uint4*)(yp + (size_t)(b * L2_ + g * 64) * H_);
    for (int k = tid; k < 64 * 32; k += TB) {
      int r = k >> 5, c = k & 31;
      yp_lds[r * 32 + (c ^ (r & 31))] = src[k];  // swizzle kills bank conflicts
    }
    const float4* ys = (const float4*)(y + (size_t)(b * L2_ + g * 64) * H_);
    float4* yd = (float4*)y_lds;
    for (int k = tid; k < 64 * 64; k += TB) yd[k] = ys[k];
  }
  if (tid < H_) {
    v_s[tid] = Vw[tid];
    bvp_s[tid] = bvp[tid];
  }
  if (tid < 64) {
    ym_s[tid] = y_mask[b * L2_ + g * 64 + tid];
    bg_s[tid] = bg[g * 64 + tid];
  }
  if (tid < 128) {
    xm_s[tid] = x_mask[b * L1_ + tid];
    const int grow = (tid >> 5) * H_ + g * 32 + (tid & 31);
    bi_s[tid] = bih[grow] + bhh[grow];
  }
  if (tid < 32) {
    float hv = h0[b * H_ + g * 32 + tid];
    c_s[tid] = c0[b * H_ + g * 32 + tid];
    hn_s[tid] = hv;
    l2store(&hb[b * H_ + g * 32 + tid], hv);
  }
  const float vb = Vb[0];
  __syncthreads();
  {  // initial qpart from h0 slice (column-split of Wvp, f32)
    const int j = tid >> 1, sub = tid & 1;
    const float4* w4 =
        (const float4*)(Wvp + (size_t)j * H_ + g * 32 + sub * 16);
    const float4* hv4 = (const float4*)(hn_s + sub * 16);
    float acc = 0.f;
#pragma unroll
    for (int i = 0; i < 4; ++i) acc += dot4(w4[i], hv4[i]);
    acc += __shfl_xor(acc, 1);
    if (sub == 0) l2store(&qp[(b * 8 + g) * H_ + j], acc);
  }
  group_barrier(cnt, ++target);

  for (int t = 0; t < L1_; ++t) {
    const int xm = xm_s[t];

    // ---- q finalize (spread, sc0-L2 loads) + load prev h ------------------
    {
      const int j = tid & 255, half = tid >> 8;
      float a0, a1, a2, a3;
      l2load4(&qp[(b * 8 + half * 4) * H_ + j], a0, a1, a2, a3);
      red_s[half * 256 + j] = (a0 + a1) + (a2 + a3);
      if (tid < H_) h_s[tid] = l2load(&hb[b * H_ + tid]);
    }
    __syncthreads();
    if (tid < H_) {
      q_s[tid] = red_s[tid] + red_s[256 + tid] + bvp_s[tid] +
                 bfl(xupb[(size_t)(b * L1_ + t) * H_ + tid]);
    }
    __syncthreads();

    // ---- B: scores for l-slice [g*64, g*64+64), yp from swizzled LDS ------
    {
      const int l = tid & 63, sub = tid >> 6;
      float acc = 0.f;
#pragma unroll
      for (int i = 0; i < 4; ++i) {
        uint4 u = yp_lds[l * 32 + ((sub * 4 + i) ^ (l & 31))];
        const int h = sub * 32 + i * 8;
        acc += v_s[h + 0] * ftanh(q_s[h + 0] + bfl(u.x));
        acc += v_s[h + 1] * ftanh(q_s[h + 1] + bfh(u.x));
        acc += v_s[h + 2] * ftanh(q_s[h + 2] + bfl(u.y));
        acc += v_s[h + 3] * ftanh(q_s[h + 3] + bfh(u.y));
        acc += v_s[h + 4] * ftanh(q_s[h + 4] + bfl(u.z));
        acc += v_s[h + 5] * ftanh(q_s[h + 5] + bfh(u.z));
        acc += v_s[h + 6] * ftanh(q_s[h + 6] + bfl(u.w));
        acc += v_s[h + 7] * ftanh(q_s[h + 7] + bfh(u.w));
      }
      red_s[l * 9 + sub] = acc;  // stride 9 (2-way max, free)
    }
    __syncthreads();
    if (tid < 64) {
      float s = vb;
#pragma unroll
      for (int k = 0; k < 8; ++k) s += red_s[tid * 9 + k];
      // |s| <= |Vb| + sum|v| ~ 13 -> exp never overflows; no global max
      float e = ym_s[tid] ? 0.f : fexp2(s * LOG2E_);
      e_s[tid] = e;
      float ss = e;
#pragma unroll
      for (int off = 32; off >= 1; off >>= 1) ss += __shfl_xor(ss, off);
      if (tid == 0) l2store(&esb[b * 8 + g], ss);
    }
    __syncthreads();

    // ---- ct partial over the l-slice (y from LDS) -------------------------
    {
      const int d = tid & 255, part = tid >> 8;
      float acc = 0.f;
#pragma unroll 8
      for (int i = 0; i < 32; ++i)
        acc += e_s[part * 32 + i] * y_lds[(part * 32 + i) * 256 + d];
      red_s[tid] = acc;
    }
    __syncthreads();
    if (tid < H_)
      l2store(&ctp[(b * 8 + g) * H_ + tid], red_s[tid] + red_s[tid + 256]);
    group_barrier(cnt, ++target);

    // ---- ct finalize (spread, sc0-L2 loads) + merge -----------------------
    if (tid < 8) esum_s[tid] = l2load(&esb[b * 8 + tid]);
    {
      const int j = tid & 255, half = tid >> 8;
      float a0, a1, a2, a3;
      l2load4(&ctp[(b * 8 + half * 4) * H_ + j], a0, a1, a2, a3);
      red_s[half * 256 + j] = (a0 + a1) + (a2 + a3);
      if (tid < H_) mg_s[tid] = x[(size_t)(b * L1_ + t) * H_ + tid];
    }
    __syncthreads();
    if (tid < H_) {
      float tot = esum_s[0] + esum_s[1] + esum_s[2] + esum_s[3] + esum_s[4] +
                  esum_s[5] + esum_s[6] + esum_s[7];
      mg_s[H_ + tid] = (red_s[tid] + red_s[256 + tid]) * frcp(tot);
    }
    __syncthreads();

    // ---- E: li-slice [g*64, g*64+64), Wg bf16 -----------------------------
    {
      const int o = tid >> 3, sub = tid & 7;
      const uint4* wrow = (const uint4*)(wgb + (size_t)(g * 64 + o) * 512);
      const float4* m4 = (const float4*)mg_s;
      float acc = 0.f;
#pragma unroll
      for (int j = 0; j < 8; ++j) {
        uint4 u = wrow[sub + 8 * j];
        float4 ma = m4[(sub + 8 * j) * 2], mb = m4[(sub + 8 * j) * 2 + 1];
        acc += bfl(u.x) * ma.x + bfh(u.x) * ma.y + bfl(u.y) * ma.z +
               bfh(u.y) * ma.w + bfl(u.z) * mb.x + bfh(u.z) * mb.y +
               bfl(u.w) * mb.z + bfh(u.w) * mb.w;
      }
      acc += __shfl_xor(acc, 1);
      acc += __shfl_xor(acc, 2);
      acc += __shfl_xor(acc, 4);
      if (sub == 0) {
        float gt = fsig(acc + bg_s[o]);
        l2store(&lib[b * 512 + g * 64 + o], xm ? 0.f : gt * mg_s[g * 64 + o]);
      }
    }
    group_barrier(cnt, ++target);

    // ---- F: gates for h-dims [g*32, g*32+32), Wih/Whh bf16 ----------------
    li_s[tid] = l2load(&lib[b * 512 + tid]);
    __syncthreads();
    {
      const int r = tid >> 2, sub = tid & 3;
      const int grow = (r >> 5) * H_ + g * 32 + (r & 31);
      const uint4* wi = (const uint4*)(wihb + (size_t)grow * 512);
      const uint4* wh = (const uint4*)(whhb + (size_t)grow * 256);
      const float4* l4 = (const float4*)li_s;
      const float4* h4 = (const float4*)h_s;
      float acc = 0.f;
#pragma unroll
      for (int j = 0; j < 16; ++j) {
        uint4 u = wi[sub + 4 * j];
        float4 a = l4[(sub + 4 * j) * 2], c2 = l4[(sub + 4 * j) * 2 + 1];
        acc += bfl(u.x) * a.x + bfh(u.x) * a.y + bfl(u.y) * a.z +
               bfh(u.y) * a.w + bfl(u.z) * c2.x + bfh(u.z) * c2.y +
               bfl(u.w) * c2.z + bfh(u.w) * c2.w;
      }
#pragma unroll
      for (int j = 0; j < 8; ++j) {
        uint4 u = wh[sub + 4 * j];
        float4 a = h4[(sub + 4 * j) * 2], c2 = h4[(sub + 4 * j) * 2 + 1];
        acc += bfl(u.x) * a.x + bfh(u.x) * a.y + bfl(u.y) * a.z +
               bfh(u.y) * a.w + bfl(u.z) * c2.x + bfh(u.z) * c2.y +
               bfl(u.w) * c2.z + bfh(u.w) * c2.w;
      }
      acc += __shfl_xor(acc, 1);
      acc += __shfl_xor(acc, 2);
      if (sub == 0) gate_s[r] = acc + bi_s[r];
    }
    __syncthreads();
    if (tid < 32) {
      float ii = gate_s[tid], ff = gate_s[32 + tid];
      float gg = gate_s[64 + tid], oo = gate_s[96 + tid];
      float cn = fsig(ff) * c_s[tid] + fsig(ii) * ftanh(gg);
      float hn = xm ? 0.f : fsig(oo) * ftanh(cn);
      c_s[tid] = cn;
      hn_s[tid] = hn;
      l2store(&hb[b * H_ + g * 32 + tid], hn);
      out[(size_t)(b * L1_ + t) * H_ + g * 32 + tid] = hn;
    }
    __syncthreads();

    // ---- A': qpart for next step from new h slice (Wvp f32) ---------------
    {
      const int j = tid >> 1, sub = tid & 1;
      const float4* w4 =
          (const float4*)(Wvp + (size_t)j * H_ + g * 32 + sub * 16);
      const float4* hv4 = (const float4*)(hn_s + sub * 16);
      float acc = 0.f;
#pragma unroll
      for (int i = 0; i < 4; ++i) acc += dot4(w4[i], hv4[i]);
      acc += __shfl_xor(acc, 1);
      if (sub == 0) l2store(&qp[(b * 8 + g) * H_ + j], acc);
    }
    group_barrier(cnt, ++target);
  }
}

extern "C" void kernel_launch(void* const* d_in, const int* in_sizes, int n_in,
                              void* d_out, int out_size, void* d_ws,
                              size_t ws_size, hipStream_t stream) {
  const float* x = (const float*)d_in[0];
  const int* x_mask = (const int*)d_in[1];
  const float* y = (const float*)d_in[2];
  const int* y_mask = (const int*)d_in[3];
  const float* h0 = (const float*)d_in[4];
  const float* c0 = (const float*)d_in[5];
  const float* Wq = (const float*)d_in[6];
  const float* bq = (const float*)d_in[7];
  const float* Wup = (const float*)d_in[8];
  const float* bup = (const float*)d_in[9];
  const float* Wvp = (const float*)d_in[10];
  const float* bvp = (const float*)d_in[11];
  const float* Vw = (const float*)d_in[12];
  const float* Vb = (const float*)d_in[13];
  const float* Wg = (const float*)d_in[14];
  const float* bg = (const float*)d_in[15];
  const float* Wih = (const float*)d_in[16];
  const float* Whh = (const float*)d_in[17];
  const float* bih = (const float*)d_in[18];
  const float* bhh = (const float*)d_in[19];

  float* out = (float*)d_out;
  char* ws = (char*)d_ws;

  hipMemsetAsync(ws + BAR_OFF, 0, 4096, stream);  // barrier counters -> 0
  proj_kernel<<<dim3(640), dim3(256), 0, stream>>>(
      y, Wq, bq, x, Wup, bup, (__hip_bfloat16*)(ws + YP_OFF),
      (__hip_bfloat16*)(ws + XUP_OFF));
  wconv_kernel<<<dim3(1024), dim3(256), 0, stream>>>(
      Wg, Wih, Whh, (unsigned short*)(ws + WGB_OFF),
      (unsigned short*)(ws + WIHB_OFF), (unsigned short*)(ws + WHHB_OFF));
  scan_kernel<<<dim3(B_ * GRP), dim3(TB), 0, stream>>>(
      x, x_mask, y, y_mask, h0, c0, Wvp, bvp, Vw, Vb, bg, bih, bhh, ws, out);
}

// Round 11
// 1282.359 us; speedup vs baseline: 1.8900x; 1.0255x over previous
//
#include <hip/hip_runtime.h>
#include <hip/hip_bf16.h>

// GatedMatchRNN: B=32, L1=128, L2=512, H=256
// Round 11: r10 base (XCD-local L2 comm, GRP=8, 3 barriers, bf16 weights)
// + tanh addition identity in phase B: tanh(q+yp) = (tau+T)/(1+tau*T) with
// T = tanh(yp) precomputed ONCE into LDS (f32, XOR-swizzled) and
// tau = tanh(q) per step. Halves the trans-op count of the dominant phase.

#define B_ 32
#define L1_ 128
#define L2_ 512
#define H_ 256
#define GRP 8
#define TB 512
#define LOG2E_ 1.4426950408889634f

// ws layout (bytes)
#define YP_OFF   0u                        // bf16 [32][512][256] = 8 MB
#define XUP_OFF  (8u << 20)                // bf16 [32][128][256] = 2 MB
#define QP_OFF   (10u << 20)               // f32 [32][8][256] = 256 KB
#define CTP_OFF  (QP_OFF + (256u << 10))   // f32 [32][8][256] = 256 KB
#define ES_OFF   (CTP_OFF + (256u << 10))  // f32 [32][8] (padded 4 KB)
#define LI_OFF   (ES_OFF + (4u << 10))     // f32 [32][512] = 64 KB
#define HB_OFF   (LI_OFF + (64u << 10))    // f32 [32][256] = 32 KB
#define BAR_OFF  (HB_OFF + (32u << 10))    // uint counters [32][32] = 4 KB
#define WGB_OFF  (BAR_OFF + (4u << 10))    // bf16 Wg = 512 KB
#define WIHB_OFF (WGB_OFF + (512u << 10))  // bf16 Wih = 1 MB
#define WHHB_OFF (WIHB_OFF + (1024u << 10))// bf16 Whh = 512 KB
// end ~12.6 MB (ws >= 16 MB, proven round 2)

__device__ __forceinline__ float fexp2(float x) {
#if __has_builtin(__builtin_amdgcn_exp2f)
  return __builtin_amdgcn_exp2f(x);
#else
  return exp2f(x);
#endif
}
__device__ __forceinline__ float frcp(float x) {
#if __has_builtin(__builtin_amdgcn_rcpf)
  return __builtin_amdgcn_rcpf(x);
#else
  return 1.0f / x;
#endif
}
__device__ __forceinline__ float ftanh(float x) {
  return 1.0f - 2.0f * frcp(1.0f + fexp2(x * (2.0f * LOG2E_)));
}
__device__ __forceinline__ float fsig(float x) {
  return frcp(1.0f + fexp2(-x * LOG2E_));
}
__device__ __forceinline__ float dot4(float4 a, float4 b) {
  return a.x * b.x + a.y * b.y + a.z * b.z + a.w * b.w;
}
__device__ __forceinline__ float bfl(unsigned u) {
  return __uint_as_float(u << 16);
}
__device__ __forceinline__ float bfh(unsigned u) {
  return __uint_as_float(u & 0xffff0000u);
}
__device__ __forceinline__ unsigned short f2bf(float f) {
  __hip_bfloat16 b = __float2bfloat16(f);
  return *reinterpret_cast<unsigned short*>(&b);
}

// ---- XCD-local L2 comm primitives (r10-proven) ----
__device__ __forceinline__ void l2store(float* p, float v) {
  asm volatile("global_store_dword %0, %1, off" ::"v"(p), "v"(v) : "memory");
}
__device__ __forceinline__ float l2load(const float* p) {
  float v;
  asm volatile("global_load_dword %0, %1, off sc0\n\ts_waitcnt vmcnt(0)"
               : "=&v"(v)
               : "v"(p)
               : "memory");
  return v;
}
__device__ __forceinline__ void l2load4(const float* p, float& a, float& b,
                                        float& c, float& d) {
  asm volatile(
      "global_load_dword %0, %4, off sc0\n\t"
      "global_load_dword %1, %4, off offset:1024 sc0\n\t"
      "global_load_dword %2, %4, off offset:2048 sc0\n\t"
      "global_load_dword %3, %4, off offset:3072 sc0\n\t"
      "s_waitcnt vmcnt(0)"
      : "=&v"(a), "=&v"(b), "=&v"(c), "=&v"(d)
      : "v"(p)
      : "memory");
}

// r8/r10-proven barrier (memory-side counters).
__device__ __forceinline__ void group_barrier(unsigned* cnt, unsigned target) {
  asm volatile("s_waitcnt vmcnt(0)" ::: "memory");
  __syncthreads();
  if (threadIdx.x == 0) {
    __hip_atomic_fetch_add(cnt, 1u, __ATOMIC_RELAXED,
                           __HIP_MEMORY_SCOPE_AGENT);
    while (__hip_atomic_load(cnt, __ATOMIC_RELAXED,
                             __HIP_MEMORY_SCOPE_AGENT) < GRP * target) {
      __builtin_amdgcn_s_sleep(1);
    }
  }
  __syncthreads();
  asm volatile("" ::: "memory");
}

// ---------------------------------------------------------------------------
// Projection: blocks 0..511 -> yp (bf16), 512..639 -> xup (bf16).
// ---------------------------------------------------------------------------
__global__ __launch_bounds__(256) void proj_kernel(
    const float* __restrict__ y, const float* __restrict__ Wq,
    const float* __restrict__ bq, const float* __restrict__ x,
    const float* __restrict__ Wup, const float* __restrict__ bup,
    __hip_bfloat16* __restrict__ yp, __hip_bfloat16* __restrict__ xup) {
  __shared__ float As[32 * 256];
  const int blk = blockIdx.x;
  const int tid = threadIdx.x;
  const float* src;
  const float* W;
  const float* bias;
  __hip_bfloat16* dst;
  int row0;
  if (blk < 512) {
    src = y; W = Wq; bias = bq; dst = yp; row0 = blk * 32;
  } else {
    src = x; W = Wup; bias = bup; dst = xup; row0 = (blk - 512) * 32;
  }
  const float4* s4 = (const float4*)(src + (size_t)row0 * H_);
  float4* A4 = (float4*)As;
#pragma unroll
  for (int i = 0; i < 8; ++i) A4[i * 256 + tid] = s4[i * 256 + tid];
  __syncthreads();

  const float4* w4 = (const float4*)(W + (size_t)tid * H_);
  float acc[32];
#pragma unroll
  for (int r = 0; r < 32; ++r) acc[r] = 0.0f;
  for (int kc = 0; kc < 64; ++kc) {
    float4 w = w4[kc];
#pragma unroll
    for (int r = 0; r < 32; ++r) acc[r] += dot4(A4[r * 64 + kc], w);
  }
  const float bb = bias[tid];
#pragma unroll 4
  for (int r = 0; r < 32; ++r)
    dst[(size_t)(row0 + r) * H_ + tid] = __float2bfloat16(acc[r] + bb);
}

// ---------------------------------------------------------------------------
// Weight conversion: Wg(512x512), Wih(1024x512), Whh(1024x256) -> bf16 in ws.
// ---------------------------------------------------------------------------
__global__ __launch_bounds__(256) void wconv_kernel(
    const float* __restrict__ Wg, const float* __restrict__ Wih,
    const float* __restrict__ Whh, unsigned short* __restrict__ wgb,
    unsigned short* __restrict__ wihb, unsigned short* __restrict__ whhb) {
  const int e = blockIdx.x * 256 + threadIdx.x;  // float4 index
  const float* src;
  unsigned short* dst;
  int off;
  if (e < 65536) {
    src = Wg; dst = wgb; off = e;
  } else if (e < 196608) {
    src = Wih; dst = wihb; off = e - 65536;
  } else {
    src = Whh; dst = whhb; off = e - 196608;
  }
  float4 v = ((const float4*)src)[off];
  ushort4 o;
  o.x = f2bf(v.x); o.y = f2bf(v.y); o.z = f2bf(v.z); o.w = f2bf(v.w);
  ((ushort4*)dst)[off] = o;
}

// ---------------------------------------------------------------------------
// Scan: block (b,g); b = blk&31 (XCD-local groups), g = blk>>5. 512 threads.
// ---------------------------------------------------------------------------
__global__ __launch_bounds__(TB) void scan_kernel(
    const float* __restrict__ x, const int* __restrict__ x_mask,
    const float* __restrict__ y, const int* __restrict__ y_mask,
    const float* __restrict__ h0, const float* __restrict__ c0,
    const float* __restrict__ Wvp, const float* __restrict__ bvp,
    const float* __restrict__ Vw, const float* __restrict__ Vb,
    const float* __restrict__ bg, const float* __restrict__ bih,
    const float* __restrict__ bhh, char* __restrict__ ws,
    float* __restrict__ out) {
  const int blk = blockIdx.x;
  const int b = blk & 31;   // batch; its 8 g-blocks share one XCD (r8-proven)
  const int g = blk >> 5;   // slice
  const int tid = threadIdx.x;

  const __hip_bfloat16* yp = (const __hip_bfloat16*)(ws + YP_OFF);
  const unsigned short* xupb = (const unsigned short*)(ws + XUP_OFF);
  float* qp = (float*)(ws + QP_OFF);
  float* ctp = (float*)(ws + CTP_OFF);
  float* esb = (float*)(ws + ES_OFF);
  float* lib = (float*)(ws + LI_OFF);
  float* hb = (float*)(ws + HB_OFF);
  unsigned* cnt = (unsigned*)(ws + BAR_OFF) + b * 32;  // 128B per batch
  const unsigned short* wgb = (const unsigned short*)(ws + WGB_OFF);
  const unsigned short* wihb = (const unsigned short*)(ws + WIHB_OFF);
  const unsigned short* whhb = (const unsigned short*)(ws + WHHB_OFF);

  __shared__ float4 T_lds[64 * 64];  // 64 KB f32 tanh(yp), XOR-swizzled
  __shared__ float y_lds[64 * 256];  // 64 KB
  __shared__ __align__(16) float h_s[H_];
  __shared__ float tau_s[H_];        // tanh(q)
  __shared__ float vt_s[H_];         // v * tanh(q)
  __shared__ float v_s[H_];
  __shared__ float bvp_s[H_];
  __shared__ float e_s[64];
  __shared__ __align__(16) float mg_s[2 * H_];
  __shared__ __align__(16) float li_s[2 * H_];
  __shared__ float gate_s[128];
  __shared__ float red_s[64 * 9];
  __shared__ float esum_s[8];
  __shared__ __align__(16) float c_s[32];
  __shared__ __align__(16) float hn_s[32];
  __shared__ float bg_s[64];
  __shared__ float bi_s[128];
  __shared__ int ym_s[64];
  __shared__ int xm_s[L1_];

  unsigned target = 0;

  // ---- stage t-invariant data: T = tanh(yp) in f32, XOR-swizzled ----
  {
    const uint4* src = (const uint4*)(yp + (size_t)(b * L2_ + g * 64) * H_);
    for (int k = tid; k < 64 * 32; k += TB) {
      int r = k >> 5, c5 = k & 31;  // 8 bf16 -> 2 float4 chunks (2c5, 2c5+1)
      uint4 u = src[k];
      float4 a, d;
      a.x = ftanh(bfl(u.x)); a.y = ftanh(bfh(u.x));
      a.z = ftanh(bfl(u.y)); a.w = ftanh(bfh(u.y));
      d.x = ftanh(bfl(u.z)); d.y = ftanh(bfh(u.z));
      d.z = ftanh(bfl(u.w)); d.w = ftanh(bfh(u.w));
      T_lds[r * 64 + ((2 * c5) ^ r)] = a;
      T_lds[r * 64 + ((2 * c5 + 1) ^ r)] = d;
    }
    const float4* ys = (const float4*)(y + (size_t)(b * L2_ + g * 64) * H_);
    float4* yd = (float4*)y_lds;
    for (int k = tid; k < 64 * 64; k += TB) yd[k] = ys[k];
  }
  if (tid < H_) {
    v_s[tid] = Vw[tid];
    bvp_s[tid] = bvp[tid];
  }
  if (tid < 64) {
    ym_s[tid] = y_mask[b * L2_ + g * 64 + tid];
    bg_s[tid] = bg[g * 64 + tid];
  }
  if (tid < 128) {
    xm_s[tid] = x_mask[b * L1_ + tid];
    const int grow = (tid >> 5) * H_ + g * 32 + (tid & 31);
    bi_s[tid] = bih[grow] + bhh[grow];
  }
  if (tid < 32) {
    float hv = h0[b * H_ + g * 32 + tid];
    c_s[tid] = c0[b * H_ + g * 32 + tid];
    hn_s[tid] = hv;
    l2store(&hb[b * H_ + g * 32 + tid], hv);
  }
  const float vb = Vb[0];
  __syncthreads();
  {  // initial qpart from h0 slice (column-split of Wvp, f32)
    const int j = tid >> 1, sub = tid & 1;
    const float4* w4 =
        (const float4*)(Wvp + (size_t)j * H_ + g * 32 + sub * 16);
    const float4* hv4 = (const float4*)(hn_s + sub * 16);
    float acc = 0.f;
#pragma unroll
    for (int i = 0; i < 4; ++i) acc += dot4(w4[i], hv4[i]);
    acc += __shfl_xor(acc, 1);
    if (sub == 0) l2store(&qp[(b * 8 + g) * H_ + j], acc);
  }
  group_barrier(cnt, ++target);

  for (int t = 0; t < L1_; ++t) {
    const int xm = xm_s[t];

    // ---- q finalize (spread, sc0-L2 loads) + tau/vt + load prev h ---------
    {
      const int j = tid & 255, half = tid >> 8;
      float a0, a1, a2, a3;
      l2load4(&qp[(b * 8 + half * 4) * H_ + j], a0, a1, a2, a3);
      red_s[half * 256 + j] = (a0 + a1) + (a2 + a3);
      if (tid < H_) h_s[tid] = l2load(&hb[b * H_ + tid]);
    }
    __syncthreads();
    if (tid < H_) {
      float q = red_s[tid] + red_s[256 + tid] + bvp_s[tid] +
                bfl(xupb[(size_t)(b * L1_ + t) * H_ + tid]);
      float ta = ftanh(q);
      tau_s[tid] = ta;
      vt_s[tid] = v_s[tid] * ta;
    }
    __syncthreads();

    // ---- B: s[l] = Vb + sum_h v*(tau+T)/(1+tau*T), T from LDS -------------
    {
      const int l = tid & 63, sub = tid >> 6;  // h-range wave-uniform
      float acc = 0.f;
#pragma unroll
      for (int i = 0; i < 4; ++i) {
        float4 Ta = T_lds[l * 64 + ((sub * 8 + 2 * i) ^ l)];
        float4 Tb = T_lds[l * 64 + ((sub * 8 + 2 * i + 1) ^ l)];
        const int h = sub * 32 + i * 8;
        acc += __builtin_fmaf(v_s[h + 0], Ta.x, vt_s[h + 0]) *
               frcp(__builtin_fmaf(tau_s[h + 0], Ta.x, 1.0f));
        acc += __builtin_fmaf(v_s[h + 1], Ta.y, vt_s[h + 1]) *
               frcp(__builtin_fmaf(tau_s[h + 1], Ta.y, 1.0f));
        acc += __builtin_fmaf(v_s[h + 2], Ta.z, vt_s[h + 2]) *
               frcp(__builtin_fmaf(tau_s[h + 2], Ta.z, 1.0f));
        acc += __builtin_fmaf(v_s[h + 3], Ta.w, vt_s[h + 3]) *
               frcp(__builtin_fmaf(tau_s[h + 3], Ta.w, 1.0f));
        acc += __builtin_fmaf(v_s[h + 4], Tb.x, vt_s[h + 4]) *
               frcp(__builtin_fmaf(tau_s[h + 4], Tb.x, 1.0f));
        acc += __builtin_fmaf(v_s[h + 5], Tb.y, vt_s[h + 5]) *
               frcp(__builtin_fmaf(tau_s[h + 5], Tb.y, 1.0f));
        acc += __builtin_fmaf(v_s[h + 6], Tb.z, vt_s[h + 6]) *
               frcp(__builtin_fmaf(tau_s[h + 6], Tb.z, 1.0f));
        acc += __builtin_fmaf(v_s[h + 7], Tb.w, vt_s[h + 7]) *
               frcp(__builtin_fmaf(tau_s[h + 7], Tb.w, 1.0f));
      }
      red_s[l * 9 + sub] = acc;  // stride 9 (2-way max, free)
    }
    __syncthreads();
    if (tid < 64) {
      float s = vb;
#pragma unroll
      for (int k = 0; k < 8; ++k) s += red_s[tid * 9 + k];
      // |s| <= |Vb| + sum|v| ~ 13 -> exp never overflows; no global max
      float e = ym_s[tid] ? 0.f : fexp2(s * LOG2E_);
      e_s[tid] = e;
      float ss = e;
#pragma unroll
      for (int off = 32; off >= 1; off >>= 1) ss += __shfl_xor(ss, off);
      if (tid == 0) l2store(&esb[b * 8 + g], ss);
    }
    __syncthreads();

    // ---- ct partial over the l-slice (y from LDS) -------------------------
    {
      const int d = tid & 255, part = tid >> 8;
      float acc = 0.f;
#pragma unroll 8
      for (int i = 0; i < 32; ++i)
        acc += e_s[part * 32 + i] * y_lds[(part * 32 + i) * 256 + d];
      red_s[tid] = acc;
    }
    __syncthreads();
    if (tid < H_)
      l2store(&ctp[(b * 8 + g) * H_ + tid], red_s[tid] + red_s[tid + 256]);
    group_barrier(cnt, ++target);

    // ---- ct finalize (spread, sc0-L2 loads) + merge -----------------------
    if (tid < 8) esum_s[tid] = l2load(&esb[b * 8 + tid]);
    {
      const int j = tid & 255, half = tid >> 8;
      float a0, a1, a2, a3;
      l2load4(&ctp[(b * 8 + half * 4) * H_ + j], a0, a1, a2, a3);
      red_s[half * 256 + j] = (a0 + a1) + (a2 + a3);
      if (tid < H_) mg_s[tid] = x[(size_t)(b * L1_ + t) * H_ + tid];
    }
    __syncthreads();
    if (tid < H_) {
      float tot = esum_s[0] + esum_s[1] + esum_s[2] + esum_s[3] + esum_s[4] +
                  esum_s[5] + esum_s[6] + esum_s[7];
      mg_s[H_ + tid] = (red_s[tid] + red_s[256 + tid]) * frcp(tot);
    }
    __syncthreads();

    // ---- E: li-slice [g*64, g*64+64), Wg bf16 -----------------------------
    {
      const int o = tid >> 3, sub = tid & 7;
      const uint4* wrow = (const uint4*)(wgb + (size_t)(g * 64 + o) * 512);
      const float4* m4 = (const float4*)mg_s;
      float acc = 0.f;
#pragma unroll
      for (int j = 0; j < 8; ++j) {
        uint4 u = wrow[sub + 8 * j];
        float4 ma = m4[(sub + 8 * j) * 2], mb = m4[(sub + 8 * j) * 2 + 1];
        acc += bfl(u.x) * ma.x + bfh(u.x) * ma.y + bfl(u.y) * ma.z +
               bfh(u.y) * ma.w + bfl(u.z) * mb.x + bfh(u.z) * mb.y +
               bfl(u.w) * mb.z + bfh(u.w) * mb.w;
      }
      acc += __shfl_xor(acc, 1);
      acc += __shfl_xor(acc, 2);
      acc += __shfl_xor(acc, 4);
      if (sub == 0) {
        float gt = fsig(acc + bg_s[o]);
        l2store(&lib[b * 512 + g * 64 + o], xm ? 0.f : gt * mg_s[g * 64 + o]);
      }
    }
    group_barrier(cnt, ++target);

    // ---- F: gates for h-dims [g*32, g*32+32), Wih/Whh bf16 ----------------
    li_s[tid] = l2load(&lib[b * 512 + tid]);
    __syncthreads();
    {
      const int r = tid >> 2, sub = tid & 3;
      const int grow = (r >> 5) * H_ + g * 32 + (r & 31);
      const uint4* wi = (const uint4*)(wihb + (size_t)grow * 512);
      const uint4* wh = (const uint4*)(whhb + (size_t)grow * 256);
      const float4* l4 = (const float4*)li_s;
      const float4* h4 = (const float4*)h_s;
      float acc = 0.f;
#pragma unroll
      for (int j = 0; j < 16; ++j) {
        uint4 u = wi[sub + 4 * j];
        float4 a = l4[(sub + 4 * j) * 2], c2 = l4[(sub + 4 * j) * 2 + 1];
        acc += bfl(u.x) * a.x + bfh(u.x) * a.y + bfl(u.y) * a.z +
               bfh(u.y) * a.w + bfl(u.z) * c2.x + bfh(u.z) * c2.y +
               bfl(u.w) * c2.z + bfh(u.w) * c2.w;
      }
#pragma unroll
      for (int j = 0; j < 8; ++j) {
        uint4 u = wh[sub + 4 * j];
        float4 a = h4[(sub + 4 * j) * 2], c2 = h4[(sub + 4 * j) * 2 + 1];
        acc += bfl(u.x) * a.x + bfh(u.x) * a.y + bfl(u.y) * a.z +
               bfh(u.y) * a.w + bfl(u.z) * c2.x + bfh(u.z) * c2.y +
               bfl(u.w) * c2.z + bfh(u.w) * c2.w;
      }
      acc += __shfl_xor(acc, 1);
      acc += __shfl_xor(acc, 2);
      if (sub == 0) gate_s[r] = acc + bi_s[r];
    }
    __syncthreads();
    if (tid < 32) {
      float ii = gate_s[tid], ff = gate_s[32 + tid];
      float gg = gate_s[64 + tid], oo = gate_s[96 + tid];
      float cn = fsig(ff) * c_s[tid] + fsig(ii) * ftanh(gg);
      float hn = xm ? 0.f : fsig(oo) * ftanh(cn);
      c_s[tid] = cn;
      hn_s[tid] = hn;
      l2store(&hb[b * H_ + g * 32 + tid], hn);
      out[(size_t)(b * L1_ + t) * H_ + g * 32 + tid] = hn;
    }
    __syncthreads();

    // ---- A': qpart for next step from new h slice (Wvp f32) ---------------
    {
      const int j = tid >> 1, sub = tid & 1;
      const float4* w4 =
          (const float4*)(Wvp + (size_t)j * H_ + g * 32 + sub * 16);
      const float4* hv4 = (const float4*)(hn_s + sub * 16);
      float acc = 0.f;
#pragma unroll
      for (int i = 0; i < 4; ++i) acc += dot4(w4[i], hv4[i]);
      acc += __shfl_xor(acc, 1);
      if (sub == 0) l2store(&qp[(b * 8 + g) * H_ + j], acc);
    }
    group_barrier(cnt, ++target);
  }
}

extern "C" void kernel_launch(void* const* d_in, const int* in_sizes, int n_in,
                              void* d_out, int out_size, void* d_ws,
                              size_t ws_size, hipStream_t stream) {
  const float* x = (const float*)d_in[0];
  const int* x_mask = (const int*)d_in[1];
  const float* y = (const float*)d_in[2];
  const int* y_mask = (const int*)d_in[3];
  const float* h0 = (const float*)d_in[4];
  const float* c0 = (const float*)d_in[5];
  const float* Wq = (const float*)d_in[6];
  const float* bq = (const float*)d_in[7];
  const float* Wup = (const float*)d_in[8];
  const float* bup = (const float*)d_in[9];
  const float* Wvp = (const float*)d_in[10];
  const float* bvp = (const float*)d_in[11];
  const float* Vw = (const float*)d_in[12];
  const float* Vb = (const float*)d_in[13];
  const float* Wg = (const float*)d_in[14];
  const float* bg = (const float*)d_in[15];
  const float* Wih = (const float*)d_in[16];
  const float* Whh = (const float*)d_in[17];
  const float* bih = (const float*)d_in[18];
  const float* bhh = (const float*)d_in[19];

  float* out = (float*)d_out;
  char* ws = (char*)d_ws;

  hipMemsetAsync(ws + BAR_OFF, 0, 4096, stream);  // barrier counters -> 0
  proj_kernel<<<dim3(640), dim3(256), 0, stream>>>(
      y, Wq, bq, x, Wup, bup, (__hip_bfloat16*)(ws + YP_OFF),
      (__hip_bfloat16*)(ws + XUP_OFF));
  wconv_kernel<<<dim3(1024), dim3(256), 0, stream>>>(
      Wg, Wih, Whh, (unsigned short*)(ws + WGB_OFF),
      (unsigned short*)(ws + WIHB_OFF), (unsigned short*)(ws + WHHB_OFF));
  scan_kernel<<<dim3(B_ * GRP), dim3(TB), 0, stream>>>(
      x, x_mask, y, y_mask, h0, c0, Wvp, bvp, Vw, Vb, bg, bih, bhh, ws, out);
}